// Round 2
// baseline (898.958 us; speedup 1.0000x reference)
//
#include <hip/hip_runtime.h>

typedef __attribute__((ext_vector_type(8))) short bf16x8;
typedef __attribute__((ext_vector_type(4))) float f32x4;

__device__ __forceinline__ float b2f(unsigned short u) {
  unsigned int v = ((unsigned int)u) << 16;
  return __builtin_bit_cast(float, v);
}
__device__ __forceinline__ unsigned short f2b(float f) {
  unsigned int v = __builtin_bit_cast(unsigned int, f);
  v += 0x7FFFu + ((v >> 16) & 1u);
  return (unsigned short)(v >> 16);
}

// One block = one window. 512 threads = 8 waves.
// LDS regions (16384 bf16 each = 32KB):
//  sm0: x (bf16, natural [n][c]) -> later v packed as PV-B fragments
//  sm1: dw-out packed A-frags    -> later per-wave P scratch (4KB each)
//  sm2: q packed A-frags         -> later attn_out packed A-frags
//  sm3: k packed A-frags
// Packed-A layout: elem (row n, col c) at frag f=(n/16)*8+(c/32),
//   lane l'=(n%16)+16*((c%32)/8), byte j'=c%8:  addr = f*512 + l'*8 + j'
__global__ __launch_bounds__(512) void winattn_kernel(
    const float* __restrict__ xg,
    const float* __restrict__ dww0, const float* __restrict__ dwb0,
    const float* __restrict__ pww0, const float* __restrict__ pwb0,
    const float* __restrict__ dww1, const float* __restrict__ dwb1,
    const float* __restrict__ pww1, const float* __restrict__ pwb1,
    const float* __restrict__ dww2, const float* __restrict__ dwb2,
    const float* __restrict__ pww2, const float* __restrict__ pwb2,
    const float* __restrict__ bt,
    const float* __restrict__ pjw, const float* __restrict__ pjb,
    const int* __restrict__ rel,
    float* __restrict__ outg)
{
  __shared__ __align__(16) unsigned short smem[65536];
  unsigned short* sm0 = smem;
  unsigned short* sm1 = smem + 16384;
  unsigned short* sm2 = smem + 32768;
  unsigned short* sm3 = smem + 49152;

  const int tid  = threadIdx.x;
  const int lane = tid & 63;
  const int wv   = tid >> 6;
  const int lq   = lane >> 4;
  const int lc   = lane & 15;
  const int b    = blockIdx.x;

  const f32x4 zero4 = {0.f, 0.f, 0.f, 0.f};

  // ---- load x[b] (64x256 f32 = 64KB) -> bf16 in LDS (32KB) ----
  {
    const float4* gx = (const float4*)(xg + (size_t)b * 16384);
    ushort4* sx = (ushort4*)sm0;
#pragma unroll
    for (int i = 0; i < 8; ++i) {
      const float4 v = gx[tid + 512 * i];
      ushort4 u;
      u.x = f2b(v.x); u.y = f2b(v.y); u.z = f2b(v.z); u.w = f2b(v.w);
      sx[tid + 512 * i] = u;
    }
  }
  __syncthreads();

  const float* dwwA[3] = {dww0, dww1, dww2};
  const float* dwbA[3] = {dwb0, dwb1, dwb2};
  const float* pwwA[3] = {pww0, pww1, pww2};
  const float* pwbA[3] = {pwb0, pwb1, pwb2};

  const int cch = tid & 255;   // channel for dw conv
  const int hlf = tid >> 8;    // which 4 l-rows

#pragma unroll
  for (int p = 0; p < 3; ++p) {
    // ---- depthwise 3x3 + bias + relu  (x natural -> sm1 packed) ----
    {
      float w9[9];
#pragma unroll
      for (int t = 0; t < 9; ++t) w9[t] = dwwA[p][cch * 9 + t];
      const float bsv = dwbA[p][cch];
      const int l0 = hlf * 4;
      float row[3][8];
#pragma unroll
      for (int w = 0; w < 8; ++w)
        row[0][w] = (hlf == 0) ? 0.f : b2f(sm0[((l0 - 1) * 8 + w) * 256 + cch]);
#pragma unroll
      for (int w = 0; w < 8; ++w)
        row[1][w] = b2f(sm0[(l0 * 8 + w) * 256 + cch]);
#pragma unroll
      for (int li = 0; li < 4; ++li) {
        const int l = l0 + li;
        const bool haveNext = (l < 7);
#pragma unroll
        for (int w = 0; w < 8; ++w)
          row[2][w] = haveNext ? b2f(sm0[((l + 1) * 8 + w) * 256 + cch]) : 0.f;
#pragma unroll
        for (int w = 0; w < 8; ++w) {
          float acc = bsv;
#pragma unroll
          for (int dl = 0; dl < 3; ++dl) {
#pragma unroll
            for (int dc = 0; dc < 3; ++dc) {
              const int w2 = w + dc - 1;
              if (w2 >= 0 && w2 < 8) acc = fmaf(w9[dl * 3 + dc], row[dl][w2], acc);
            }
          }
          acc = fmaxf(acc, 0.f);
          const int n  = l * 8 + w;
          const int f  = (n >> 4) * 8 + (cch >> 5);
          const int lp = (n & 15) + 16 * ((cch & 31) >> 3);
          sm1[f * 512 + lp * 8 + (cch & 7)] = f2b(acc);
        }
#pragma unroll
        for (int w = 0; w < 8; ++w) { row[0][w] = row[1][w]; row[1][w] = row[2][w]; }
      }
    }
    __syncthreads();

    // ---- pointwise GEMM: out[n][co] = sum_ci dw[n][ci] * W[co][ci] + b[co] ----
    {
      const float* W = pwwA[p];
      f32x4 acc[4][2];
#pragma unroll
      for (int i = 0; i < 4; ++i)
#pragma unroll
        for (int t = 0; t < 2; ++t) acc[i][t] = zero4;
#pragma unroll
      for (int kk = 0; kk < 8; ++kk) {
        bf16x8 a[4], bb[2];
#pragma unroll
        for (int i = 0; i < 4; ++i)
          a[i] = *(const bf16x8*)&sm1[(i * 8 + kk) * 512 + lane * 8];
#pragma unroll
        for (int t = 0; t < 2; ++t) {
          const int co = 16 * (2 * wv + t) + lc;
          const float4* wp = (const float4*)(W + co * 256 + 32 * kk + 8 * lq);
          const float4 wa = wp[0];
          const float4 wc = wp[1];
          bf16x8 bv;
          bv[0] = (short)f2b(wa.x); bv[1] = (short)f2b(wa.y);
          bv[2] = (short)f2b(wa.z); bv[3] = (short)f2b(wa.w);
          bv[4] = (short)f2b(wc.x); bv[5] = (short)f2b(wc.y);
          bv[6] = (short)f2b(wc.z); bv[7] = (short)f2b(wc.w);
          bb[t] = bv;
        }
#pragma unroll
        for (int i = 0; i < 4; ++i)
#pragma unroll
          for (int t = 0; t < 2; ++t)
            acc[i][t] = __builtin_amdgcn_mfma_f32_16x16x32_bf16(a[i], bb[t], acc[i][t], 0, 0, 0);
      }
      // epilogue: + bias, store bf16 into destination layout
#pragma unroll
      for (int t = 0; t < 2; ++t) {
        const int co = 16 * (2 * wv + t) + lc;
        const float pb = pwbA[p][co];
#pragma unroll
        for (int i = 0; i < 4; ++i) {
#pragma unroll
          for (int r = 0; r < 4; ++r) {
            const float v = acc[i][t][r] + pb;
            const int n = 16 * i + 4 * lq + r;
            if (p < 2) {
              unsigned short* dst = (p == 0) ? sm2 : sm3;
              const int f  = i * 8 + (co >> 5);
              const int lp = (n & 15) + 16 * ((co & 31) >> 3);
              dst[f * 512 + lp * 8 + (co & 7)] = f2b(v);
            } else {
              // v: pack as PV B-operand fragments
              const int h   = co >> 5;
              const int ct2 = (co >> 4) & 1;
              const int kt  = i >> 1;
              const int g   = (h * 2 + ct2) * 2 + kt;
              const int tl  = n & 31;
              const int lp  = (tl >> 3) * 16 + (co & 15);
              sm0[g * 512 + lp * 8 + (tl & 7)] = f2b(v);
            }
          }
        }
      }
    }
    __syncthreads();
  }

  // ---- attention: wave wv handles head h = wv ----
  float rsum[4][4];
  {
    const int h = wv;
    f32x4 s[4][4];
    {
      bf16x8 aq[4];
#pragma unroll
      for (int i = 0; i < 4; ++i)
        aq[i] = *(const bf16x8*)&sm2[(i * 8 + h) * 512 + lane * 8];
#pragma unroll
      for (int ct = 0; ct < 4; ++ct) {
        const bf16x8 bk = *(const bf16x8*)&sm3[(ct * 8 + h) * 512 + lane * 8];
#pragma unroll
        for (int i = 0; i < 4; ++i)
          s[i][ct] = __builtin_amdgcn_mfma_f32_16x16x32_bf16(aq[i], bk, zero4, 0, 0, 0);
      }
    }
    const float scale = 0.17677669529663687f;
    // scale + relative-position bias
#pragma unroll
    for (int i = 0; i < 4; ++i) {
#pragma unroll
      for (int r = 0; r < 4; ++r) {
        const int n = 16 * i + 4 * lq + r;
        const int* relrow = rel + n * 64;
#pragma unroll
        for (int ct = 0; ct < 4; ++ct) {
          const int m = 16 * ct + lc;
          const float bv = bt[relrow[m] * 8 + h];
          s[i][ct][r] = s[i][ct][r] * scale + bv;
        }
      }
    }
    // softmax over m (cols): reduce over ct in-reg + 16-lane group shuffles
    float mx[4][4];
#pragma unroll
    for (int i = 0; i < 4; ++i) {
#pragma unroll
      for (int r = 0; r < 4; ++r) {
        float m0 = fmaxf(fmaxf(s[i][0][r], s[i][1][r]), fmaxf(s[i][2][r], s[i][3][r]));
        m0 = fmaxf(m0, __shfl_xor(m0, 1));
        m0 = fmaxf(m0, __shfl_xor(m0, 2));
        m0 = fmaxf(m0, __shfl_xor(m0, 4));
        m0 = fmaxf(m0, __shfl_xor(m0, 8));
        mx[i][r] = m0;
      }
    }
#pragma unroll
    for (int i = 0; i < 4; ++i) {
#pragma unroll
      for (int r = 0; r < 4; ++r) {
        float s0 = 0.f;
#pragma unroll
        for (int ct = 0; ct < 4; ++ct) {
          const float e = __expf(s[i][ct][r] - mx[i][r]);
          s[i][ct][r] = e;
          s0 += e;
        }
        s0 += __shfl_xor(s0, 1);
        s0 += __shfl_xor(s0, 2);
        s0 += __shfl_xor(s0, 4);
        s0 += __shfl_xor(s0, 8);
        rsum[i][r] = s0;
      }
    }
    // PV: two K-halves through per-wave LDS P scratch
    f32x4 o[4][2];
#pragma unroll
    for (int i = 0; i < 4; ++i)
#pragma unroll
      for (int t = 0; t < 2; ++t) o[i][t] = zero4;
    unsigned short* Ppk = sm1 + wv * 2048;
#pragma unroll
    for (int kk = 0; kk < 2; ++kk) {
#pragma unroll
      for (int td = 0; td < 2; ++td) {
        const int ct = 2 * kk + td;
#pragma unroll
        for (int i = 0; i < 4; ++i) {
#pragma unroll
          for (int r = 0; r < 4; ++r) {
            const int np = 4 * lq + r;
            const int cm = 16 * td + lc;
            Ppk[i * 512 + (np + 16 * (cm >> 3)) * 8 + (cm & 7)] = f2b(s[i][ct][r]);
          }
        }
      }
      bf16x8 pa[4];
#pragma unroll
      for (int i = 0; i < 4; ++i)
        pa[i] = *(const bf16x8*)&Ppk[i * 512 + lane * 8];
#pragma unroll
      for (int ct2 = 0; ct2 < 2; ++ct2) {
        const bf16x8 vb = *(const bf16x8*)&sm0[((h * 2 + ct2) * 2 + kk) * 512 + lane * 8];
#pragma unroll
        for (int i = 0; i < 4; ++i)
          o[i][ct2] = __builtin_amdgcn_mfma_f32_16x16x32_bf16(pa[i], vb, o[i][ct2], 0, 0, 0);
      }
    }
    // normalize + write attn_out into sm2 frag (i, h)
#pragma unroll
    for (int ct2 = 0; ct2 < 2; ++ct2) {
#pragma unroll
      for (int i = 0; i < 4; ++i) {
#pragma unroll
        for (int r = 0; r < 4; ++r) {
          const float v = o[i][ct2][r] / rsum[i][r];
          const int np = 4 * lq + r;
          const int lp = np + 16 * (2 * ct2 + (lc >> 3));
          sm2[(i * 8 + h) * 512 + lp * 8 + (lc & 7)] = f2b(v);
        }
      }
    }
  }
  __syncthreads();

  // ---- projection GEMM + bias -> global (f32) ----
  {
    f32x4 acc[4][2];
#pragma unroll
    for (int i = 0; i < 4; ++i)
#pragma unroll
      for (int t = 0; t < 2; ++t) acc[i][t] = zero4;
#pragma unroll
    for (int kk = 0; kk < 8; ++kk) {
      bf16x8 a[4], bb[2];
#pragma unroll
      for (int i = 0; i < 4; ++i)
        a[i] = *(const bf16x8*)&sm2[(i * 8 + kk) * 512 + lane * 8];
#pragma unroll
      for (int t = 0; t < 2; ++t) {
        const int co = 16 * (2 * wv + t) + lc;
        const float4* wp = (const float4*)(pjw + co * 256 + 32 * kk + 8 * lq);
        const float4 wa = wp[0];
        const float4 wc = wp[1];
        bf16x8 bv;
        bv[0] = (short)f2b(wa.x); bv[1] = (short)f2b(wa.y);
        bv[2] = (short)f2b(wa.z); bv[3] = (short)f2b(wa.w);
        bv[4] = (short)f2b(wc.x); bv[5] = (short)f2b(wc.y);
        bv[6] = (short)f2b(wc.z); bv[7] = (short)f2b(wc.w);
        bb[t] = bv;
      }
#pragma unroll
      for (int i = 0; i < 4; ++i)
#pragma unroll
        for (int t = 0; t < 2; ++t)
          acc[i][t] = __builtin_amdgcn_mfma_f32_16x16x32_bf16(a[i], bb[t], acc[i][t], 0, 0, 0);
    }
    float* og = outg + (size_t)b * 16384;
#pragma unroll
    for (int t = 0; t < 2; ++t) {
      const int co = 16 * (2 * wv + t) + lc;
      const float pb = pjb[co];
#pragma unroll
      for (int i = 0; i < 4; ++i) {
#pragma unroll
        for (int r = 0; r < 4; ++r) {
          const int n = 16 * i + 4 * lq + r;
          og[n * 256 + co] = acc[i][t][r] + pb;
        }
      }
    }
  }
}

extern "C" void kernel_launch(void* const* d_in, const int* in_sizes, int n_in,
                              void* d_out, int out_size, void* d_ws, size_t ws_size,
                              hipStream_t stream) {
  (void)in_sizes; (void)n_in; (void)d_ws; (void)ws_size; (void)out_size;
  const float* x    = (const float*)d_in[0];
  const float* qdww = (const float*)d_in[1];
  const float* qdwb = (const float*)d_in[2];
  const float* qpww = (const float*)d_in[3];
  const float* qpwb = (const float*)d_in[4];
  const float* kdww = (const float*)d_in[5];
  const float* kdwb = (const float*)d_in[6];
  const float* kpww = (const float*)d_in[7];
  const float* kpwb = (const float*)d_in[8];
  const float* vdww = (const float*)d_in[9];
  const float* vdwb = (const float*)d_in[10];
  const float* vpww = (const float*)d_in[11];
  const float* vpwb = (const float*)d_in[12];
  const float* bt   = (const float*)d_in[13];
  const float* pjw  = (const float*)d_in[14];
  const float* pjb  = (const float*)d_in[15];
  const int* rel    = (const int*)d_in[16];
  float* out        = (float*)d_out;

  hipLaunchKernelGGL(winattn_kernel, dim3(4096), dim3(512), 0, stream,
                     x, qdww, qdwb, qpww, qpwb, kdww, kdwb, kpww, kpwb,
                     vdww, vdwb, vpww, vpwb, bt, pjw, pjb, rel, out);
}